// Round 12
// baseline (98.882 us; speedup 1.0000x reference)
//
#include <hip/hip_runtime.h>

// DWN pipeline v12: ONE dispatch, TWO fence-free barriers, NO h1T round-trip.
//
// Evidence: R11 (fence-free, 3 barriers, h1T materialized) passed with clean
// replays -> relaxed agent atomics + cumulative flags fully validated. But
// kernel ~40-54us: relaxed atomics bypass L1/L2, so the h1T round-trip
// (4MB write-through + 12MB coherent-point reads) ran at L3 latency with no
// cache reuse. Fix: fuse P2 into P3 — recompute the 6 h1 values per o2-task
// from bitsT (uniform u64 atomic broadcasts, 192KB L3-resident) + luts1
// (read-only input -> normal cached loads). Kills h1T entirely and barrier
// #2. 3x redundant luts1 gathers are L2-cached and cheap.
//
//   P1: thermometer encode -> transposed bit-pack  bitsT[3072][8] u64
//   barrier #1 (fence-free flags)
//   P23: per o2-task: 6 inline h1 (6 idx1 rows cached + 36 bitsT broadcasts
//        + 6 luts1 gathers) -> 6-D multilinear fold -> h2T (relaxed store)
//   barrier #2 (arrival all; detection only by 5 P4 blocks)
//   P4: group-sum / tau (exact 10x10 two-level)    out[512][10]
//
// FP order verbatim from the harness-verified kernels -> absmax 0.0.
// Flags cumulative + all-thread base load (replay-safe); spin caps turn
// surprises into wrong answers, not hangs.

#define FEAT   1024
#define O1     2000
#define O2     1000
#define NCLS   10
#define NB     256
#define NT     1024
#define NWAVES (NB * (NT / 64))   // 4096 global waves
#define P4BLKS ((NCLS * 8 + 15) / 16)   // 5

#define WS_BITS_OFF  0
#define WS_H2_OFF    (256 << 10)                 // 256 KB

#define SCOPE_AGENT __HIP_MEMORY_SCOPE_AGENT

// Cumulative flags: +2 per block per launch -> equal at launch boundaries.
__device__ unsigned g_flags[NB];

__global__ __launch_bounds__(NT, 4) void dwn_v12(
    const float* __restrict__ x,       // [512,1024]
    const float* __restrict__ thr,     // [1024,3] == flat [3072]
    const float* __restrict__ luts1,   // [2000,64]
    const int*   __restrict__ idx1,    // [2000,6] in [0,3072)
    const float* __restrict__ luts2,   // [1000,64]
    const int*   __restrict__ idx2,    // [1000,6] in [0,2000)
    float* __restrict__ out,           // [512,10]
    unsigned long long* __restrict__ bitsT,  // [3072][8]
    float* __restrict__ h2T)                 // [1000][512]
{
    const int t    = threadIdx.x;
    const int lane = t & 63;
    const int wl   = t >> 6;                 // wave in block, 0..15
    const int b    = blockIdx.x;
    const int gw   = (b << 4) | wl;          // global wave id, 0..4095

    // Replay-safe base: ALL threads read the block's own flag.
    const unsigned base =
        __hip_atomic_load(&g_flags[b], __ATOMIC_RELAXED, SCOPE_AGENT);

    // ---- P1: thermometer encode + transposed bit-pack (R11 verbatim) ----
    {
        const int w8    = wl & 7;
        const int row   = (w8 << 6) | lane;
        const int fbase = (b << 2) | ((wl >> 3) << 1);
#pragma unroll
        for (int ff = 0; ff < 2; ++ff) {
            const int f = fbase + ff;
            const float xv = x[(size_t)row * FEAT + f];
            const float* tp = thr + (size_t)f * 3;   // wave-uniform
#pragma unroll
            for (int j = 0; j < 3; ++j) {
                const unsigned long long m = __ballot(xv > tp[j]);
                if (lane == 0)
                    __hip_atomic_store(&bitsT[(size_t)(f * 3 + j) * 8 + w8],
                                       m, __ATOMIC_RELAXED, SCOPE_AGENT);
            }
        }
    }

    // ---- fence-free barrier #1 ----
    __syncthreads();                         // drains vmcnt for all waves
    if (t == 0)
        __hip_atomic_store(&g_flags[b], base + 1u, __ATOMIC_RELAXED, SCOPE_AGENT);
    if (t < 64) {
        const unsigned tg = base + 1u;
        for (int spin = 0; spin < (1 << 20); ++spin) {
            const unsigned v0 = __hip_atomic_load(&g_flags[t],       __ATOMIC_RELAXED, SCOPE_AGENT);
            const unsigned v1 = __hip_atomic_load(&g_flags[t + 64],  __ATOMIC_RELAXED, SCOPE_AGENT);
            const unsigned v2 = __hip_atomic_load(&g_flags[t + 128], __ATOMIC_RELAXED, SCOPE_AGENT);
            const unsigned v3 = __hip_atomic_load(&g_flags[t + 192], __ATOMIC_RELAXED, SCOPE_AGENT);
            if (__all((v0 >= tg) & (v1 >= tg) & (v2 >= tg) & (v3 >= tg))) break;
            __builtin_amdgcn_s_sleep(2);
        }
    }
    __syncthreads();

    // ---- P23: layer 1 fused into layer 2 ----
    // Task = (o2, w): wave handles rows rr = w*64+lane of output o2.
    for (int task = gw; task < O2 * 8; task += NWAVES) {
        const int o  = task >> 3;
        const int w  = task & 7;
        const int rr = (w << 6) | lane;
        const int* ip = idx2 + o * 6;        // wave-uniform, read-only input

        // 6 inline h1 values. idx1/luts1 are read-only inputs -> normal
        // cached loads; bitsT is cross-block -> uniform u64 atomic
        // broadcasts (one L3 line each, L3-resident).
        float xv[6];
#pragma unroll
        for (int k = 0; k < 6; ++k) {
            const int o1 = ip[k];
            const int2* iq = (const int2*)(idx1 + o1 * 6);  // wave-uniform
            const int2 q0 = iq[0], q1 = iq[1], q2 = iq[2];
            const unsigned long long m0 = __hip_atomic_load(&bitsT[(size_t)q0.x * 8 + w], __ATOMIC_RELAXED, SCOPE_AGENT);
            const unsigned long long m1 = __hip_atomic_load(&bitsT[(size_t)q0.y * 8 + w], __ATOMIC_RELAXED, SCOPE_AGENT);
            const unsigned long long m2 = __hip_atomic_load(&bitsT[(size_t)q1.x * 8 + w], __ATOMIC_RELAXED, SCOPE_AGENT);
            const unsigned long long m3 = __hip_atomic_load(&bitsT[(size_t)q1.y * 8 + w], __ATOMIC_RELAXED, SCOPE_AGENT);
            const unsigned long long m4 = __hip_atomic_load(&bitsT[(size_t)q2.x * 8 + w], __ATOMIC_RELAXED, SCOPE_AGENT);
            const unsigned long long m5 = __hip_atomic_load(&bitsT[(size_t)q2.y * 8 + w], __ATOMIC_RELAXED, SCOPE_AGENT);
            const int code = ((int)((m0 >> lane) & 1ull) << 5)
                           | ((int)((m1 >> lane) & 1ull) << 4)
                           | ((int)((m2 >> lane) & 1ull) << 3)
                           | ((int)((m3 >> lane) & 1ull) << 2)
                           | ((int)((m4 >> lane) & 1ull) << 1)
                           |  (int)((m5 >> lane) & 1ull);
            xv[k] = luts1[o1 * 64 + code];   // gather in uniform 256B row
        }

        // 6-D multilinear fold, LSB-first — verbatim fp order.
        const float4* lp = (const float4*)(luts2 + (size_t)o * 64);  // uniform
        float v[16];
#pragma unroll
        for (int q = 0; q < 16; ++q) {       // fold x5 (bit0), x4 (bit1)
            float4 e = lp[q];
            float u0 = e.x + xv[5] * (e.y - e.x);
            float u1 = e.z + xv[5] * (e.w - e.z);
            v[q] = u0 + xv[4] * (u1 - u0);
        }
#pragma unroll
        for (int q = 0; q < 8; ++q) v[q] = v[2*q] + xv[3] * (v[2*q+1] - v[2*q]);
#pragma unroll
        for (int q = 0; q < 4; ++q) v[q] = v[2*q] + xv[2] * (v[2*q+1] - v[2*q]);
#pragma unroll
        for (int q = 0; q < 2; ++q) v[q] = v[2*q] + xv[1] * (v[2*q+1] - v[2*q]);
        __hip_atomic_store(&h2T[(size_t)o * 512 + rr],
                           v[0] + xv[0] * (v[1] - v[0]),
                           __ATOMIC_RELAXED, SCOPE_AGENT);
    }

    // ---- fence-free barrier #2 (arrival all; detection only P4 blocks) ----
    __syncthreads();
    if (t == 0)
        __hip_atomic_store(&g_flags[b], base + 2u, __ATOMIC_RELAXED, SCOPE_AGENT);
    if (b >= P4BLKS) return;                 // blocks 5..255 done
    if (t < 64) {
        const unsigned tg = base + 2u;
        for (int spin = 0; spin < (1 << 20); ++spin) {
            const unsigned v0 = __hip_atomic_load(&g_flags[t],       __ATOMIC_RELAXED, SCOPE_AGENT);
            const unsigned v1 = __hip_atomic_load(&g_flags[t + 64],  __ATOMIC_RELAXED, SCOPE_AGENT);
            const unsigned v2 = __hip_atomic_load(&g_flags[t + 128], __ATOMIC_RELAXED, SCOPE_AGENT);
            const unsigned v3 = __hip_atomic_load(&g_flags[t + 192], __ATOMIC_RELAXED, SCOPE_AGENT);
            if (__all((v0 >= tg) & (v1 >= tg) & (v2 >= tg) & (v3 >= tg))) break;
            __builtin_amdgcn_s_sleep(2);
        }
    }
    __syncthreads();

    // ---- P4: group sum / tau, exact 10x10 two-level order (verbatim) ----
    if (gw < NCLS * 8) {
        const int c  = gw >> 3;
        const int rr = ((gw & 7) << 6) | lane;
        float s = 0.0f;
#pragma unroll
        for (int p = 0; p < 10; ++p) {
            float s2 = 0.0f;
#pragma unroll
            for (int j = 0; j < 10; ++j) {
                const float hv = __hip_atomic_load(
                    &h2T[(size_t)(c * 100 + p * 10 + j) * 512 + rr],
                    __ATOMIC_RELAXED, SCOPE_AGENT);
                s2 += hv;
            }
            s += s2;
        }
        out[(size_t)rr * NCLS + c] = s / 3.3333333f;
    }
}

extern "C" void kernel_launch(void* const* d_in, const int* in_sizes, int n_in,
                              void* d_out, int out_size, void* d_ws, size_t ws_size,
                              hipStream_t stream) {
    const float* x     = (const float*)d_in[0];
    const float* thr   = (const float*)d_in[1];
    const float* luts1 = (const float*)d_in[2];
    const int*   idx1  = (const int*)  d_in[3];
    const float* luts2 = (const float*)d_in[4];
    const int*   idx2  = (const int*)  d_in[5];
    float* out = (float*)d_out;

    char* ws = (char*)d_ws;
    unsigned long long* bitsT = (unsigned long long*)(ws + WS_BITS_OFF);
    float* h2T = (float*)(ws + WS_H2_OFF);

    dwn_v12<<<NB, NT, 0, stream>>>(x, thr, luts1, idx1, luts2, idx2,
                                   out, bitsT, h2T);
}

// Round 13
// 79.016 us; speedup vs baseline: 1.2514x; 1.2514x over previous
//
#include <hip/hip_runtime.h>

// DWN pipeline, fused block-local (R5 champion, 78.6us total) + XCD-L2 table
// prefetch.
//
// Evidence: R6 (reps=2 diag on this exact body): ~35us/pass, VALUBusy 7.8%,
// LDS conflicts nil, FETCH 43.5MB/pass vs 0.84MB unique table bytes ->
// cold-cache scattered-gather latency through a poison-dirtied L2/L3 is the
// cost (luts1[o*64+code] touches ~64 lines/wave-instr at HBM-miss latency).
// R11/R12 (atomic transposed family) and R9/R10 (block-local recompute) are
// all 20-45us worse end-to-end; the fused family wins.
//
// Change vs R5 (semantically inert -> absmax 0.0 preserved): at kernel
// start, each block issues coalesced loads of a 1/32 slice of the four
// tables (840KB total; 26KB/block, <=3 vec loads/thread). The 32 blocks per
// XCD collectively pull the ENTIRE table set into their own 4MB L2, in the
// shadow of P1's ballot work (keep-alive asm sits just before the first
// __syncthreads, so no early waitcnt stall). P2/P3 gathers then hit L2
// (~200cy) instead of poisoned L3/HBM (~450-900cy).

#define BATCH 512
#define FEAT  1024
#define NBITS (FEAT * 3)      // 3072
#define O1    2000
#define O2    1000
#define NCLS  10
#define G     2               // batch rows per block
#define NB    (BATCH / G)     // 256 blocks
#define NT    1024            // 16 waves

__global__ __launch_bounds__(NT, 4) void dwn_fused_pf(
    const float* __restrict__ x,       // [512,1024]
    const float* __restrict__ thr,     // [1024,3] == flat [3072]
    const float* __restrict__ luts1,   // [2000,64]
    const int*   __restrict__ idx1,    // [2000,6] in [0,3072)
    const float* __restrict__ luts2,   // [1000,64]
    const int*   __restrict__ idx2,    // [1000,6] in [0,2000)
    float* __restrict__ out)           // [512,10]
{
    __shared__ unsigned s_bw[G][NBITS / 32];   // 768 B, bit-packed thermo
    __shared__ float s_h1[G][O1];              // 16 KB
    __shared__ float s_h2[G][O2];              // 8 KB
    __shared__ float s_part[G * NCLS * 10];    // 800 B

    const int t    = threadIdx.x;
    const int lane = t & 63;
    const int wl   = t >> 6;                   // wave in block, 0..15
    const int b0   = blockIdx.x * G;

    // ---- Table prefetch: slice s of 32; whole table set lands in this
    // XCD's L2 while P1 runs. Loads kept alive (not elided) via asm below.
    const int s = blockIdx.x & 31;
    float4 pfa = make_float4(0.f, 0.f, 0.f, 0.f);
    float4 pfb = pfa;
    int4   pfc = make_int4(0, 0, 0, 0);
    int4   pfd = pfc;
    {
        const float4* l1 = (const float4*)luts1;   // 32000 float4
        const float4* l2 = (const float4*)luts2;   // 16000 float4
        const int4*   i1 = (const int4*)idx1;      //  3000 int4
        const int4*   i2 = (const int4*)idx2;      //  1500 int4
        if (t < 1000) pfa = l1[s * 1000 + t];
        if (t < 500)  pfb = l2[s * 500 + t];
        if (t < 94) { const int ii = s * 94 + t; if (ii < 3000) pfc = i1[ii]; }
        if (t < 47) { const int ii = s * 47 + t; if (ii < 1500) pfd = i2[ii]; }
    }

    // ---- P1: thermometer encode -> bit-packed LDS via ballot (R5 verbatim) ----
#pragma unroll
    for (int k = 0; k < 6; ++k) {
        const int task = k * 16 + wl;          // 0..95, exact
        const int r  = task & 1;
        const int g  = task >> 1;              // 0..47
        const int bi = (g << 6) | lane;
        const int f  = bi / 3;                 // magic-mul
        const float xv = x[(b0 + r) * FEAT + f];
        const float tv = thr[bi];              // coalesced 256B/wave
        const unsigned long long m = __ballot(xv > tv);
        if (lane == 0) {
            s_bw[r][2 * g]     = (unsigned)m;
            s_bw[r][2 * g + 1] = (unsigned)(m >> 32);
        }
    }

    // Keep the prefetch loads alive; by now they completed under P1.
    asm volatile("" ::
        "v"(pfa.x), "v"(pfa.y), "v"(pfa.z), "v"(pfa.w),
        "v"(pfb.x), "v"(pfb.y), "v"(pfb.z), "v"(pfb.w),
        "v"(pfc.x), "v"(pfc.y), "v"(pfc.z), "v"(pfc.w),
        "v"(pfd.x), "v"(pfd.y), "v"(pfd.z), "v"(pfd.w));
    __syncthreads();

    // ---- P2: layer 1 — pure 6-bit table lookup (R5 verbatim) ----
#pragma unroll
    for (int k = 0; k < 4; ++k) {
        const int i = t + k * NT;
        if (i < G * O1) {
            const int o = i >> 1;
            const int r = i & 1;
            const int2* ip = (const int2*)(idx1 + o * 6);  // o*24 is 8B-aligned
            const int2 p0 = ip[0], p1 = ip[1], p2 = ip[2];
            const int code =
                  ((int)((s_bw[r][p0.x >> 5] >> (p0.x & 31)) & 1u) << 5)
                | ((int)((s_bw[r][p0.y >> 5] >> (p0.y & 31)) & 1u) << 4)
                | ((int)((s_bw[r][p1.x >> 5] >> (p1.x & 31)) & 1u) << 3)
                | ((int)((s_bw[r][p1.y >> 5] >> (p1.y & 31)) & 1u) << 2)
                | ((int)((s_bw[r][p2.x >> 5] >> (p2.x & 31)) & 1u) << 1)
                |  (int)((s_bw[r][p2.y >> 5] >> (p2.y & 31)) & 1u);
            s_h1[r][o] = luts1[o * 64 + code];
        }
    }
    __syncthreads();

    // ---- P3: layer 2 — 6-D multilinear interpolation, LSB-first fold ----
#pragma unroll
    for (int k = 0; k < 2; ++k) {
        const int i = t + k * NT;
        if (i < G * O2) {
            const int o = i >> 1;
            const int r = i & 1;
            const int2* ip = (const int2*)(idx2 + o * 6);
            const int2 p0 = ip[0], p1 = ip[1], p2 = ip[2];
            const float xv0 = s_h1[r][p0.x];
            const float xv1 = s_h1[r][p0.y];
            const float xv2 = s_h1[r][p1.x];
            const float xv3 = s_h1[r][p1.y];
            const float xv4 = s_h1[r][p2.x];
            const float xv5 = s_h1[r][p2.y];

            const float4* lp = (const float4*)(luts2 + (size_t)o * 64);
            float v[16];
#pragma unroll
            for (int q = 0; q < 16; ++q) {     // fold x5 (bit0), x4 (bit1)
                float4 e = lp[q];
                float u0 = e.x + xv5 * (e.y - e.x);
                float u1 = e.z + xv5 * (e.w - e.z);
                v[q] = u0 + xv4 * (u1 - u0);
            }
#pragma unroll
            for (int q = 0; q < 8; ++q) v[q] = v[2*q] + xv3 * (v[2*q+1] - v[2*q]);
#pragma unroll
            for (int q = 0; q < 4; ++q) v[q] = v[2*q] + xv2 * (v[2*q+1] - v[2*q]);
#pragma unroll
            for (int q = 0; q < 2; ++q) v[q] = v[2*q] + xv1 * (v[2*q+1] - v[2*q]);
            s_h2[r][o] = v[0] + xv0 * (v[1] - v[0]);
        }
    }
    __syncthreads();

    // ---- P4: group sum / tau, exact 10x10 two-level order (verbatim) ----
    if (t < G * NCLS * 10) {                   // 200 partial sums of 10
        int g = t / 10;
        int p = t % 10;
        int r   = g / NCLS;
        int cls = g % NCLS;
        const float* hp = &s_h2[r][cls * 100 + p * 10];
        float s2 = 0.0f;
#pragma unroll
        for (int j = 0; j < 10; ++j) s2 += hp[j];
        s_part[t] = s2;
    }
    __syncthreads();
    if (t < G * NCLS) {                        // 20 final sums of 10 partials
        float s2 = 0.0f;
#pragma unroll
        for (int j = 0; j < 10; ++j) s2 += s_part[t * 10 + j];
        int r   = t / NCLS;
        int cls = t % NCLS;
        out[(b0 + r) * NCLS + cls] = s2 / 3.3333333f;
    }
}

extern "C" void kernel_launch(void* const* d_in, const int* in_sizes, int n_in,
                              void* d_out, int out_size, void* d_ws, size_t ws_size,
                              hipStream_t stream) {
    const float* x     = (const float*)d_in[0];
    const float* thr   = (const float*)d_in[1];
    const float* luts1 = (const float*)d_in[2];
    const int*   idx1  = (const int*)  d_in[3];
    const float* luts2 = (const float*)d_in[4];
    const int*   idx2  = (const int*)  d_in[5];
    float* out = (float*)d_out;

    dwn_fused_pf<<<NB, NT, 0, stream>>>(x, thr, luts1, idx1, luts2, idx2, out);
}